// Round 1
// baseline (397.290 us; speedup 1.0000x reference)
//
#include <hip/hip_runtime.h>
#include <hip/hip_bf16.h>

typedef short bf16x8 __attribute__((ext_vector_type(8)));
typedef float f32x4 __attribute__((ext_vector_type(4)));

__device__ inline void gload_lds16(const void* g, void* l) {
  __builtin_amdgcn_global_load_lds((const __attribute__((address_space(1))) void*)g,
                                   (__attribute__((address_space(3))) void*)l, 16, 0, 0);
}

// ---------------- Quantization: Hadamard(32) rotate + MXFP4 quant-dequant ----------------
// One thread per group of 32. Output = q * scale (exact in bf16); the /(gs_x*gs_w)
// is folded into the GEMM epilogue.
__global__ __launch_bounds__(256) void quant_mxfp4(const float* __restrict__ in,
                                                   short* __restrict__ out,
                                                   const float* __restrict__ gs_ptr,
                                                   int n_groups) {
  int g = blockIdx.x * 256 + threadIdx.x;
  if (g >= n_groups) return;
  const float gs = gs_ptr[0];

  float t[32];
  const float4* p = (const float4*)(in + (size_t)g * 32);
#pragma unroll
  for (int i = 0; i < 8; ++i) {
    float4 v4 = p[i];
    t[4 * i + 0] = v4.x; t[4 * i + 1] = v4.y;
    t[4 * i + 2] = v4.z; t[4 * i + 3] = v4.w;
  }

  // FWHT, Sylvester order: y[j] = sum_i (-1)^popc(i&j) t[i]  (== H_syl^T t, symmetric)
#pragma unroll
  for (int s = 0; s < 5; ++s) {
    const int h = 1 << s;
#pragma unroll
    for (int i = 0; i < 32; ++i) {
      if ((i & h) == 0) {
        float a = t[i], b = t[i + h];
        t[i] = a + b;
        t[i + h] = a - b;
      }
    }
  }

  const float c = 0.17677669529663687f;  // 32^-0.5 (matches fp32 H entries)
  float v[32];
  float am = 0.0f;
#pragma unroll
  for (int i = 0; i < 32; ++i) {
    float r = t[i] * c;      // rot (fp32)
    float vi = r * gs;       // v = rot * gs (fp32, same two-step rounding as ref)
    v[i] = vi;
    am = fmaxf(am, fabsf(vi));
  }

  // scale = exp2(ceil(log2(absmax/6))), computed exactly via frexp
  float a6 = am * (1.0f / 6.0f) * 6.0f;  // keep exact division below
  a6 = am / 6.0f;
  int ex;
  float mant = frexpf(a6, &ex);          // a6 = mant * 2^ex, mant in [0.5,1)
  int e = (mant == 0.5f) ? ex - 1 : ex;
  float scale = (am > 0.0f) ? ldexpf(1.0f, e) : 1.0f;
  float inv_s = 1.0f / scale;            // power of two: exact

  short o[32] __attribute__((aligned(16)));
#pragma unroll
  for (int i = 0; i < 32; ++i) {
    float u = v[i] * inv_s;              // exact (power-of-two scale)
    float au = fabsf(u);
    // round-to-nearest e2m1 via strict midpoint compares (== searchsorted side='left')
    float q = 0.0f;
    q += (au > 0.25f) ? 0.5f : 0.0f;
    q += (au > 0.75f) ? 0.5f : 0.0f;
    q += (au > 1.25f) ? 0.5f : 0.0f;
    q += (au > 1.75f) ? 0.5f : 0.0f;
    q += (au > 2.5f)  ? 1.0f : 0.0f;
    q += (au > 3.5f)  ? 1.0f : 0.0f;
    q += (au > 5.0f)  ? 2.0f : 0.0f;
    float dqs = copysignf(q * scale, u); // exact in bf16
    union { float f; unsigned u32; } cv;
    cv.f = dqs;
    o[i] = (short)(cv.u32 >> 16);        // exact truncation (low mantissa bits are 0)
  }

#pragma unroll
  for (int j = 0; j < 4; ++j) {
    *(bf16x8*)(out + (size_t)g * 32 + 8 * j) = *(const bf16x8*)&o[8 * j];
  }
}

// ---------------- GEMM: C[m][n] = (1/(gsx*gsw)) * sum_k A[m][k]*B[n][k] + bias[n] ----------------
// m97 structure: 128x128 tile, BK=32, 4 waves (2x2 of 64x64), global_load_lds width=16.
#define BM 128
#define BN 128
#define BK 32

__global__ __launch_bounds__(256) void gemm_bt_bf16(const short* __restrict__ A,
                                                    const short* __restrict__ B,
                                                    float* __restrict__ C,
                                                    const float* __restrict__ bias,
                                                    const float* __restrict__ gsx,
                                                    const float* __restrict__ gsw,
                                                    int M, int N, int K) {
  __shared__ __align__(16) short Asl[BM * BK];
  __shared__ __align__(16) short Bsl[BN * BK];

  const int tid = threadIdx.x;
  const int w = tid >> 6;
  const int lane = tid & 63;
  const int wr = w >> 1, wc = w & 1;
  const int p = lane & 15, q = lane >> 4;

  const size_t brow = (size_t)blockIdx.y * BM;
  const size_t bcol = (size_t)blockIdx.x * BN;

  f32x4 zero = {0.f, 0.f, 0.f, 0.f};
  f32x4 acc[4][4];
#pragma unroll
  for (int m = 0; m < 4; ++m)
#pragma unroll
    for (int n = 0; n < 4; ++n) acc[m][n] = zero;

  // staging geometry: 512 chunks of 16B per tile (128 rows x 4 chunks); 2 per thread
  const int ch0 = w * 64 + lane;          // 0..255
  const int r0 = ch0 >> 2, c0 = (ch0 & 3) * 8;
  const int ch1 = 256 + ch0;              // 256..511
  const int r1 = ch1 >> 2, c1 = (ch1 & 3) * 8;
  char* aldsb = (char*)Asl + w * 1024;    // wave-uniform LDS dest
  char* bldsb = (char*)Bsl + w * 1024;

  const short* Ab = A + brow * (size_t)K;
  const short* Bb = B + bcol * (size_t)K;

  const int nkt = K / BK;
  for (int kt = 0; kt < nkt; ++kt) {
    const int k0 = kt * BK;
    gload_lds16(Ab + (size_t)r0 * K + k0 + c0, aldsb);
    gload_lds16(Ab + (size_t)r1 * K + k0 + c1, aldsb + 4096);
    gload_lds16(Bb + (size_t)r0 * K + k0 + c0, bldsb);
    gload_lds16(Bb + (size_t)r1 * K + k0 + c1, bldsb + 4096);
    __syncthreads();  // drains vmcnt then barrier: LDS tiles ready

    bf16x8 af[4], bfr[4];
#pragma unroll
    for (int m = 0; m < 4; ++m) {
      int row = wr * 64 + m * 16 + p;
      af[m] = *(const bf16x8*)(Asl + row * BK + q * 8);
    }
#pragma unroll
    for (int n = 0; n < 4; ++n) {
      int row = wc * 64 + n * 16 + p;
      bfr[n] = *(const bf16x8*)(Bsl + row * BK + q * 8);
    }
#pragma unroll
    for (int m = 0; m < 4; ++m)
#pragma unroll
      for (int n = 0; n < 4; ++n)
        acc[m][n] = __builtin_amdgcn_mfma_f32_16x16x32_bf16(af[m], bfr[n], acc[m][n], 0, 0, 0);
    __syncthreads();  // all reads done before next stage overwrites
  }

  const float inv = 1.0f / (gsx[0] * gsw[0]);
#pragma unroll
  for (int n = 0; n < 4; ++n) {
    const int col = (int)bcol + wc * 64 + n * 16 + p;
    const float bv = bias[col];
#pragma unroll
    for (int m = 0; m < 4; ++m) {
      const size_t row = brow + (size_t)(wr * 64 + m * 16 + q * 4);
#pragma unroll
      for (int r = 0; r < 4; ++r) {
        C[(row + r) * (size_t)N + col] = acc[m][n][r] * inv + bv;
      }
    }
  }
}

extern "C" void kernel_launch(void* const* d_in, const int* in_sizes, int n_in,
                              void* d_out, int out_size, void* d_ws, size_t ws_size,
                              hipStream_t stream) {
  const float* x    = (const float*)d_in[0];
  const float* wgt  = (const float*)d_in[1];
  const float* bias = (const float*)d_in[2];
  // d_in[3] = hadamard matrix (Sylvester order, hardcoded via FWHT)
  const float* wgs  = (const float*)d_in[4];
  const float* ags  = (const float*)d_in[5];

  const int N = in_sizes[2];            // 4096
  const int K = in_sizes[1] / N;        // 4096
  const int M = in_sizes[0] / K;        // 8192

  short* xq = (short*)d_ws;
  short* wq = xq + (size_t)M * K;

  const int xg = in_sizes[0] / 32;
  const int wg = in_sizes[1] / 32;
  quant_mxfp4<<<dim3((xg + 255) / 256), dim3(256), 0, stream>>>(x, xq, ags, xg);
  quant_mxfp4<<<dim3((wg + 255) / 256), dim3(256), 0, stream>>>(wgt, wq, wgs, wg);

  dim3 grid(N / BN, M / BM);
  gemm_bt_bf16<<<grid, dim3(256), 0, stream>>>(xq, wq, (float*)d_out, bias, ags, wgs, M, N, K);
}

// Round 2
// 312.437 us; speedup vs baseline: 1.2716x; 1.2716x over previous
//
#include <hip/hip_runtime.h>
#include <hip/hip_bf16.h>

typedef short bf16x8 __attribute__((ext_vector_type(8)));
typedef float f32x4 __attribute__((ext_vector_type(4)));

__device__ inline void gload_lds16(const void* g, void* l) {
  __builtin_amdgcn_global_load_lds((const __attribute__((address_space(1))) void*)g,
                                   (__attribute__((address_space(3))) void*)l, 16, 0, 0);
}

// ---------------- Quantization: Hadamard(32) rotate + MXFP4 quant-dequant ----------------
// One thread per group of 32. Output = q * scale (exact in bf16); the /(gs_x*gs_w)
// is folded into the GEMM epilogue.
__global__ __launch_bounds__(256) void quant_mxfp4(const float* __restrict__ in,
                                                   short* __restrict__ out,
                                                   const float* __restrict__ gs_ptr,
                                                   int n_groups) {
  int g = blockIdx.x * 256 + threadIdx.x;
  if (g >= n_groups) return;
  const float gs = gs_ptr[0];

  float t[32];
  const float4* p = (const float4*)(in + (size_t)g * 32);
#pragma unroll
  for (int i = 0; i < 8; ++i) {
    float4 v4 = p[i];
    t[4 * i + 0] = v4.x; t[4 * i + 1] = v4.y;
    t[4 * i + 2] = v4.z; t[4 * i + 3] = v4.w;
  }

  // FWHT, Sylvester order (H symmetric, orthonormal after *32^-0.5)
#pragma unroll
  for (int s = 0; s < 5; ++s) {
    const int h = 1 << s;
#pragma unroll
    for (int i = 0; i < 32; ++i) {
      if ((i & h) == 0) {
        float a = t[i], b = t[i + h];
        t[i] = a + b;
        t[i + h] = a - b;
      }
    }
  }

  const float c = 0.17677669529663687f;  // 32^-0.5
  float v[32];
  float am = 0.0f;
#pragma unroll
  for (int i = 0; i < 32; ++i) {
    float r = t[i] * c;
    float vi = r * gs;
    v[i] = vi;
    am = fmaxf(am, fabsf(vi));
  }

  float a6 = am / 6.0f;
  int ex;
  float mant = frexpf(a6, &ex);          // a6 = mant * 2^ex, mant in [0.5,1)
  int e = (mant == 0.5f) ? ex - 1 : ex;  // exact ceil(log2(a6))
  float scale = (am > 0.0f) ? ldexpf(1.0f, e) : 1.0f;
  float inv_s = 1.0f / scale;

  short o[32] __attribute__((aligned(16)));
#pragma unroll
  for (int i = 0; i < 32; ++i) {
    float u = v[i] * inv_s;
    float au = fabsf(u);
    float q = 0.0f;
    q += (au > 0.25f) ? 0.5f : 0.0f;
    q += (au > 0.75f) ? 0.5f : 0.0f;
    q += (au > 1.25f) ? 0.5f : 0.0f;
    q += (au > 1.75f) ? 0.5f : 0.0f;
    q += (au > 2.5f)  ? 1.0f : 0.0f;
    q += (au > 3.5f)  ? 1.0f : 0.0f;
    q += (au > 5.0f)  ? 2.0f : 0.0f;
    float dqs = copysignf(q * scale, u);
    union { float f; unsigned u32; } cv;
    cv.f = dqs;
    o[i] = (short)(cv.u32 >> 16);
  }

#pragma unroll
  for (int j = 0; j < 4; ++j) {
    *(bf16x8*)(out + (size_t)g * 32 + 8 * j) = *(const bf16x8*)&o[8 * j];
  }
}

// ---------------- 256x256 8-phase GEMM (T1+T2+T3+T4+T5), C = inv*(A@B^T) + bias ----------
// 8 waves (2M x 4N), BK=64, LDS = 2dbuf x {A,B} x 2 halves(128 rows x 64 bf16) = 128 KiB.
// Per phase: {ds_read subtile || stage 1 half-tile} -> barrier -> lgkmcnt(0) ->
// setprio(1) + 16 MFMA -> [vmcnt(4) @ph4/8] -> barrier. vmcnt never drained in-loop.

#define STAGE(mb, kt, h, ldsHalf) do {                                              \
    const short* _s = (mb) + (size_t)((h)*128 + (w << 3) + (l >> 3)) * K            \
                      + (size_t)(kt) * 64 + (size_t)csw * 8;                        \
    gload_lds16(_s, (char*)(ldsHalf) + (w << 10));                                  \
    gload_lds16(_s + ((size_t)K << 6), (char*)(ldsHalf) + (w << 10) + 8192);        \
  } while (0)

#define LOADB(bf) do {                                                              \
    const char* _bb = (const char*)&lds[bf][1][wn >> 1][0];                         \
    _Pragma("unroll")                                                               \
    for (int n = 0; n < 4; ++n) {                                                   \
      int row = (wn & 1) * 64 + n * 16 + p;                                         \
      int x5 = ((row >> 2) & 1) << 5;                                               \
      bfr[n][0] = *(const bf16x8*)(_bb + row * 128 + ((q * 16) ^ x5));              \
      bfr[n][1] = *(const bf16x8*)(_bb + row * 128 + ((64 + q * 16) ^ x5));         \
    } } while (0)

#define LOADA(bf, mq) do {                                                          \
    const char* _ab = (const char*)&lds[bf][0][wm][0];                              \
    _Pragma("unroll")                                                               \
    for (int mi = 0; mi < 2; ++mi) {                                                \
      int row = ((mq) * 2 + mi) * 16 + p;                                           \
      int x5 = ((row >> 2) & 1) << 5;                                               \
      af[mi][0] = *(const bf16x8*)(_ab + row * 128 + ((q * 16) ^ x5));              \
      af[mi][1] = *(const bf16x8*)(_ab + row * 128 + ((64 + q * 16) ^ x5));         \
    } } while (0)

#define MFMAQ(mq) do {                                                              \
    __builtin_amdgcn_s_setprio(1);                                                  \
    _Pragma("unroll")                                                               \
    for (int mi = 0; mi < 2; ++mi)                                                  \
      _Pragma("unroll")                                                             \
      for (int n = 0; n < 4; ++n) {                                                 \
        acc[(mq)*2+mi][n] = __builtin_amdgcn_mfma_f32_16x16x32_bf16(                \
            af[mi][0], bfr[n][0], acc[(mq)*2+mi][n], 0, 0, 0);                      \
        acc[(mq)*2+mi][n] = __builtin_amdgcn_mfma_f32_16x16x32_bf16(                \
            af[mi][1], bfr[n][1], acc[(mq)*2+mi][n], 0, 0, 0);                      \
      }                                                                             \
    __builtin_amdgcn_s_setprio(0);                                                  \
  } while (0)

#define MIDSYNC() do { __builtin_amdgcn_s_barrier();                                \
    asm volatile("s_waitcnt lgkmcnt(0)" ::: "memory");                              \
    __builtin_amdgcn_sched_barrier(0); } while (0)

#define ENDP() __builtin_amdgcn_s_barrier()
#define VM4()  asm volatile("s_waitcnt vmcnt(4)" ::: "memory")

__global__ __launch_bounds__(512, 2) void gemm256_8ph(const short* __restrict__ A,
                                                      const short* __restrict__ B,
                                                      float* __restrict__ C,
                                                      const float* __restrict__ bias,
                                                      const float* __restrict__ gsx,
                                                      const float* __restrict__ gsw,
                                                      int M, int N, int K) {
  __shared__ __align__(16) short lds[2][2][2][8192];  // [buf][A/B][half][128x64]

  const int tid = threadIdx.x;
  const int w = tid >> 6, l = tid & 63;
  const int wm = w >> 2, wn = w & 3;
  const int p = l & 15, q = l >> 4;
  const int csw = (l & 7) ^ (((l >> 5) & 1) << 1);  // inverse-swizzled source chunk

  // T1: XCD-aware block swizzle (nwg here is 512, divisible by 8)
  const int nwg = gridDim.x;
  int bid = blockIdx.x;
  if ((nwg & 7) == 0) bid = (bid & 7) * (nwg >> 3) + (bid >> 3);
  const int ntn = N / 256;
  const size_t brow = (size_t)(bid / ntn) * 256;
  const size_t bcol = (size_t)(bid % ntn) * 256;

  const short* Ab = A + brow * (size_t)K;
  const short* Bb = B + bcol * (size_t)K;

  f32x4 acc[8][4];
  f32x4 zero = {0.f, 0.f, 0.f, 0.f};
#pragma unroll
  for (int m = 0; m < 8; ++m)
#pragma unroll
    for (int n = 0; n < 4; ++n) acc[m][n] = zero;

  bf16x8 af[2][2], bfr[4][2];

  const int nkt = K / 64;        // 64
  const int niter = nkt / 2;     // 32

  // Prologue: tile0 (B0,B1,A0,A1 -> buf0), tile1 (B0,B1 -> buf1); wait tile0 only.
  STAGE(Bb, 0, 0, &lds[0][1][0][0]);
  STAGE(Bb, 0, 1, &lds[0][1][1][0]);
  STAGE(Ab, 0, 0, &lds[0][0][0][0]);
  STAGE(Ab, 0, 1, &lds[0][0][1][0]);
  STAGE(Bb, 1, 0, &lds[1][1][0][0]);
  STAGE(Bb, 1, 1, &lds[1][1][1][0]);
  VM4();                          // tile0's 8 loads landed; tile1-B (4) in flight
  __builtin_amdgcn_s_barrier();

  for (int i = 0; i < niter; ++i) {
    const int T = 2 * i;
    const int t1 = T + 1;
    const int t2 = (T + 2 < nkt) ? T + 2 : nkt - 1;  // clamped over-stage: dead region
    const int t3 = (T + 3 < nkt) ? T + 3 : nkt - 1;

    // ph1: tile T quad0 | stage A0(t1)->buf1
    LOADB(0); LOADA(0, 0); STAGE(Ab, t1, 0, &lds[1][0][0][0]);
    MIDSYNC(); MFMAQ(0); ENDP();
    // ph2: quad1 | stage A1(t1)->buf1
    LOADA(0, 1); STAGE(Ab, t1, 1, &lds[1][0][1][0]);
    MIDSYNC(); MFMAQ(1); ENDP();
    // ph3: quad2 | stage B0(t2)->buf0 (buf0.B dead since ph1)
    LOADA(0, 2); STAGE(Bb, t2, 0, &lds[0][1][0][0]);
    MIDSYNC(); MFMAQ(2); ENDP();
    // ph4: quad3 | stage B1(t2)->buf0 | vmcnt: tile t1 fully landed
    LOADA(0, 3); STAGE(Bb, t2, 1, &lds[0][1][1][0]);
    MIDSYNC(); MFMAQ(3); VM4(); ENDP();

    // ph5: tile t1 quad0 | stage A0(t2)->buf0 (buf0.A dead since ph4)
    LOADB(1); LOADA(1, 0); STAGE(Ab, t2, 0, &lds[0][0][0][0]);
    MIDSYNC(); MFMAQ(0); ENDP();
    // ph6: quad1 | stage A1(t2)->buf0
    LOADA(1, 1); STAGE(Ab, t2, 1, &lds[0][0][1][0]);
    MIDSYNC(); MFMAQ(1); ENDP();
    // ph7: quad2 | stage B0(t3)->buf1 (buf1.B dead since ph5)
    LOADA(1, 2); STAGE(Bb, t3, 0, &lds[1][1][0][0]);
    MIDSYNC(); MFMAQ(2); ENDP();
    // ph8: quad3 | stage B1(t3)->buf1 | vmcnt: tile t2 fully landed
    LOADA(1, 3); STAGE(Bb, t3, 1, &lds[1][1][1][0]);
    MIDSYNC(); MFMAQ(3); VM4(); ENDP();
  }

  const float inv = 1.0f / (gsx[0] * gsw[0]);
#pragma unroll
  for (int n = 0; n < 4; ++n) {
    const int col = (int)bcol + wn * 64 + n * 16 + p;
    const float bv = bias[col];
#pragma unroll
    for (int m = 0; m < 8; ++m) {
      const size_t row = brow + (size_t)(wm * 128 + m * 16 + q * 4);
#pragma unroll
      for (int r = 0; r < 4; ++r) {
        C[(row + r) * (size_t)N + col] = acc[m][n][r] * inv + bv;
      }
    }
  }
}

extern "C" void kernel_launch(void* const* d_in, const int* in_sizes, int n_in,
                              void* d_out, int out_size, void* d_ws, size_t ws_size,
                              hipStream_t stream) {
  const float* x    = (const float*)d_in[0];
  const float* wgt  = (const float*)d_in[1];
  const float* bias = (const float*)d_in[2];
  const float* wgs  = (const float*)d_in[4];
  const float* ags  = (const float*)d_in[5];

  const int N = in_sizes[2];            // 4096
  const int K = in_sizes[1] / N;        // 4096
  const int M = in_sizes[0] / K;        // 8192

  short* xq = (short*)d_ws;
  short* wq = xq + (size_t)M * K;

  const int xg = in_sizes[0] / 32;
  const int wg = in_sizes[1] / 32;
  quant_mxfp4<<<dim3((xg + 255) / 256), dim3(256), 0, stream>>>(x, xq, ags, xg);
  quant_mxfp4<<<dim3((wg + 255) / 256), dim3(256), 0, stream>>>(wgt, wq, wgs, wg);

  dim3 grid((M / 256) * (N / 256));
  gemm256_8ph<<<grid, dim3(512), 0, stream>>>(xq, wq, (float*)d_out, bias, ags, wgs, M, N, K);
}

// Round 3
// 288.147 us; speedup vs baseline: 1.3788x; 1.0843x over previous
//
#include <hip/hip_runtime.h>
#include <hip/hip_bf16.h>

typedef short bf16x8 __attribute__((ext_vector_type(8)));
typedef float f32x4 __attribute__((ext_vector_type(4)));

__device__ inline void gload_lds16(const void* g, void* l) {
  __builtin_amdgcn_global_load_lds((const __attribute__((address_space(1))) void*)g,
                                   (__attribute__((address_space(3))) void*)l, 16, 0, 0);
}

// ---------------- Quantization: Hadamard(32) rotate + MXFP4 quant-dequant ----------------
__global__ __launch_bounds__(256) void quant_mxfp4(const float* __restrict__ in,
                                                   short* __restrict__ out,
                                                   const float* __restrict__ gs_ptr,
                                                   int n_groups) {
  int g = blockIdx.x * 256 + threadIdx.x;
  if (g >= n_groups) return;
  const float gs = gs_ptr[0];

  float t[32];
  const float4* p = (const float4*)(in + (size_t)g * 32);
#pragma unroll
  for (int i = 0; i < 8; ++i) {
    float4 v4 = p[i];
    t[4 * i + 0] = v4.x; t[4 * i + 1] = v4.y;
    t[4 * i + 2] = v4.z; t[4 * i + 3] = v4.w;
  }

#pragma unroll
  for (int s = 0; s < 5; ++s) {
    const int h = 1 << s;
#pragma unroll
    for (int i = 0; i < 32; ++i) {
      if ((i & h) == 0) {
        float a = t[i], b = t[i + h];
        t[i] = a + b;
        t[i + h] = a - b;
      }
    }
  }

  const float c = 0.17677669529663687f;  // 32^-0.5
  float v[32];
  float am = 0.0f;
#pragma unroll
  for (int i = 0; i < 32; ++i) {
    float r = t[i] * c;
    float vi = r * gs;
    v[i] = vi;
    am = fmaxf(am, fabsf(vi));
  }

  float a6 = am / 6.0f;
  int ex;
  float mant = frexpf(a6, &ex);
  int e = (mant == 0.5f) ? ex - 1 : ex;  // exact ceil(log2(a6))
  float scale = (am > 0.0f) ? ldexpf(1.0f, e) : 1.0f;
  float inv_s = 1.0f / scale;

  short o[32] __attribute__((aligned(16)));
#pragma unroll
  for (int i = 0; i < 32; ++i) {
    float u = v[i] * inv_s;
    float au = fabsf(u);
    float q = 0.0f;
    q += (au > 0.25f) ? 0.5f : 0.0f;
    q += (au > 0.75f) ? 0.5f : 0.0f;
    q += (au > 1.25f) ? 0.5f : 0.0f;
    q += (au > 1.75f) ? 0.5f : 0.0f;
    q += (au > 2.5f)  ? 1.0f : 0.0f;
    q += (au > 3.5f)  ? 1.0f : 0.0f;
    q += (au > 5.0f)  ? 2.0f : 0.0f;
    float dqs = copysignf(q * scale, u);
    union { float f; unsigned u32; } cv;
    cv.f = dqs;
    o[i] = (short)(cv.u32 >> 16);
  }

#pragma unroll
  for (int j = 0; j < 4; ++j) {
    *(bf16x8*)(out + (size_t)g * 32 + 8 * j) = *(const bf16x8*)&o[8 * j];
  }
}

// ---------------- 256x256 8-phase GEMM, C = inv*(A@B^T) + bias ----------
// 8 waves (2M x 4N), BK=64, LDS = 2dbuf x {A,B} x 2 halves(128 rows x 64 bf16) = 128 KiB.
// T2 swizzle: LDS(row, chunk) holds global (row, chunk ^ (row&7)); 16B chunks.
// Reads use byte-in-row = (c ^ (row&7))<<4 -> uniform 8 accesses/bank (b128 floor).

#define STAGE(mb, kt, h, ldsHalf) do {                                              \
    const short* _s = (mb) + (size_t)((h)*128 + (w << 3) + (l >> 3)) * K            \
                      + (size_t)(kt) * 64 + (size_t)csw * 8;                        \
    gload_lds16(_s, (char*)(ldsHalf) + (w << 10));                                  \
    gload_lds16(_s + ((size_t)K << 6), (char*)(ldsHalf) + (w << 10) + 8192);        \
  } while (0)

#define LOADB(bf) do {                                                              \
    const char* _bb = (const char*)&lds[bf][1][wn >> 1][0];                         \
    _Pragma("unroll")                                                               \
    for (int n = 0; n < 4; ++n) {                                                   \
      int row = (wn & 1) * 64 + n * 16 + p;                                         \
      int xr = (row & 7) << 4;                                                      \
      bfr[n][0] = *(const bf16x8*)(_bb + row * 128 + ((q * 16) ^ xr));              \
      bfr[n][1] = *(const bf16x8*)(_bb + row * 128 + ((64 + q * 16) ^ xr));         \
    } } while (0)

#define LOADA(bf, mq) do {                                                          \
    const char* _ab = (const char*)&lds[bf][0][wm][0];                              \
    _Pragma("unroll")                                                               \
    for (int mi = 0; mi < 2; ++mi) {                                                \
      int row = ((mq) * 2 + mi) * 16 + p;                                           \
      int xr = (row & 7) << 4;                                                      \
      af[mi][0] = *(const bf16x8*)(_ab + row * 128 + ((q * 16) ^ xr));              \
      af[mi][1] = *(const bf16x8*)(_ab + row * 128 + ((64 + q * 16) ^ xr));         \
    } } while (0)

#define MFMAQ(mq) do {                                                              \
    __builtin_amdgcn_s_setprio(1);                                                  \
    _Pragma("unroll")                                                               \
    for (int mi = 0; mi < 2; ++mi)                                                  \
      _Pragma("unroll")                                                             \
      for (int n = 0; n < 4; ++n) {                                                 \
        acc[(mq)*2+mi][n] = __builtin_amdgcn_mfma_f32_16x16x32_bf16(                \
            af[mi][0], bfr[n][0], acc[(mq)*2+mi][n], 0, 0, 0);                      \
        acc[(mq)*2+mi][n] = __builtin_amdgcn_mfma_f32_16x16x32_bf16(                \
            af[mi][1], bfr[n][1], acc[(mq)*2+mi][n], 0, 0, 0);                      \
      }                                                                             \
    __builtin_amdgcn_s_setprio(0);                                                  \
  } while (0)

#define MIDSYNC() do { __builtin_amdgcn_s_barrier();                                \
    asm volatile("s_waitcnt lgkmcnt(0)" ::: "memory");                              \
    __builtin_amdgcn_sched_barrier(0); } while (0)

#define ENDP() __builtin_amdgcn_s_barrier()
#define VM4()  asm volatile("s_waitcnt vmcnt(4)" ::: "memory")

__global__ __launch_bounds__(512, 2) void gemm256_8ph(const short* __restrict__ A,
                                                      const short* __restrict__ B,
                                                      float* __restrict__ C,
                                                      const float* __restrict__ bias,
                                                      const float* __restrict__ gsx,
                                                      const float* __restrict__ gsw,
                                                      int M, int N, int K) {
  __shared__ __align__(16) short lds[2][2][2][8192];  // [buf][A/B][half][128x64]

  const int tid = threadIdx.x;
  const int w = tid >> 6, l = tid & 63;
  const int wm = w >> 2, wn = w & 3;
  const int p = l & 15, q = l >> 4;
  const int csw = (l & 7) ^ (l >> 3);  // inverse-swizzled source chunk (row&7 == l>>3)

  // T1: XCD-aware block swizzle (nwg = 512, divisible by 8)
  const int nwg = gridDim.x;
  int bid = blockIdx.x;
  if ((nwg & 7) == 0) bid = (bid & 7) * (nwg >> 3) + (bid >> 3);
  const int ntn = N / 256;
  const size_t brow = (size_t)(bid / ntn) * 256;
  const size_t bcol = (size_t)(bid % ntn) * 256;

  const short* Ab = A + brow * (size_t)K;
  const short* Bb = B + bcol * (size_t)K;

  f32x4 acc[8][4];
  f32x4 zero = {0.f, 0.f, 0.f, 0.f};
#pragma unroll
  for (int m = 0; m < 8; ++m)
#pragma unroll
    for (int n = 0; n < 4; ++n) acc[m][n] = zero;

  bf16x8 af[2][2], bfr[4][2];

  const int nkt = K / 64;        // 64
  const int niter = nkt / 2;     // 32

  // Prologue: tile0 (B0,B1,A0,A1 -> buf0), tile1 (B0,B1 -> buf1); wait tile0 only.
  STAGE(Bb, 0, 0, &lds[0][1][0][0]);
  STAGE(Bb, 0, 1, &lds[0][1][1][0]);
  STAGE(Ab, 0, 0, &lds[0][0][0][0]);
  STAGE(Ab, 0, 1, &lds[0][0][1][0]);
  STAGE(Bb, 1, 0, &lds[1][1][0][0]);
  STAGE(Bb, 1, 1, &lds[1][1][1][0]);
  VM4();                          // tile0's 8 loads landed; tile1-B (4) in flight
  __builtin_amdgcn_s_barrier();

  for (int i = 0; i < niter; ++i) {
    const int T = 2 * i;
    const int t1 = T + 1;
    const int t2 = (T + 2 < nkt) ? T + 2 : nkt - 1;  // clamped over-stage: dead region
    const int t3 = (T + 3 < nkt) ? T + 3 : nkt - 1;

    // ph1: tile T quad0 | stage A0(t1)->buf1
    LOADB(0); LOADA(0, 0); STAGE(Ab, t1, 0, &lds[1][0][0][0]);
    MIDSYNC(); MFMAQ(0); ENDP();
    // ph2: quad1 | stage A1(t1)->buf1
    LOADA(0, 1); STAGE(Ab, t1, 1, &lds[1][0][1][0]);
    MIDSYNC(); MFMAQ(1); ENDP();
    // ph3: quad2 | stage B0(t2)->buf0 (buf0.B dead since ph1)
    LOADA(0, 2); STAGE(Bb, t2, 0, &lds[0][1][0][0]);
    MIDSYNC(); MFMAQ(2); ENDP();
    // ph4: quad3 | stage B1(t2)->buf0 | vmcnt: tile t1 fully landed
    LOADA(0, 3); STAGE(Bb, t2, 1, &lds[0][1][1][0]);
    MIDSYNC(); MFMAQ(3); VM4(); ENDP();

    // ph5: tile t1 quad0 | stage A0(t2)->buf0 (buf0.A dead since ph4)
    LOADB(1); LOADA(1, 0); STAGE(Ab, t2, 0, &lds[0][0][0][0]);
    MIDSYNC(); MFMAQ(0); ENDP();
    // ph6: quad1 | stage A1(t2)->buf0
    LOADA(1, 1); STAGE(Ab, t2, 1, &lds[0][0][1][0]);
    MIDSYNC(); MFMAQ(1); ENDP();
    // ph7: quad2 | stage B0(t3)->buf1 (buf1.B dead since ph5)
    LOADA(1, 2); STAGE(Bb, t3, 0, &lds[1][1][0][0]);
    MIDSYNC(); MFMAQ(2); ENDP();
    // ph8: quad3 | stage B1(t3)->buf1 | vmcnt: tile t2 fully landed
    LOADA(1, 3); STAGE(Bb, t3, 1, &lds[1][1][1][0]);
    MIDSYNC(); MFMAQ(3); VM4(); ENDP();
  }

  const float inv = 1.0f / (gsx[0] * gsw[0]);
#pragma unroll
  for (int n = 0; n < 4; ++n) {
    const int col = (int)bcol + wn * 64 + n * 16 + p;
    const float bv = bias[col];
#pragma unroll
    for (int m = 0; m < 8; ++m) {
      const size_t row = brow + (size_t)(wm * 128 + m * 16 + q * 4);
#pragma unroll
      for (int r = 0; r < 4; ++r) {
        C[(row + r) * (size_t)N + col] = acc[m][n][r] * inv + bv;
      }
    }
  }
}

extern "C" void kernel_launch(void* const* d_in, const int* in_sizes, int n_in,
                              void* d_out, int out_size, void* d_ws, size_t ws_size,
                              hipStream_t stream) {
  const float* x    = (const float*)d_in[0];
  const float* wgt  = (const float*)d_in[1];
  const float* bias = (const float*)d_in[2];
  const float* wgs  = (const float*)d_in[4];
  const float* ags  = (const float*)d_in[5];

  const int N = in_sizes[2];            // 4096
  const int K = in_sizes[1] / N;        // 4096
  const int M = in_sizes[0] / K;        // 8192

  short* xq = (short*)d_ws;
  short* wq = xq + (size_t)M * K;

  const int xg = in_sizes[0] / 32;
  const int wg = in_sizes[1] / 32;
  quant_mxfp4<<<dim3((xg + 255) / 256), dim3(256), 0, stream>>>(x, xq, ags, xg);
  quant_mxfp4<<<dim3((wg + 255) / 256), dim3(256), 0, stream>>>(wgt, wq, wgs, wg);

  dim3 grid((M / 256) * (N / 256));
  gemm256_8ph<<<grid, dim3(512), 0, stream>>>(xq, wq, (float*)d_out, bias, ags, wgs, M, N, K);
}